// Round 3
// baseline (419.305 us; speedup 1.0000x reference)
//
#include <hip/hip_runtime.h>
#include <hip/hip_bf16.h>

#define D 128

typedef __bf16 bf16x8 __attribute__((ext_vector_type(8)));
typedef float f32x4 __attribute__((ext_vector_type(4)));

// ---------------- preprocessing ----------------

__global__ void count_kernel(const int* __restrict__ dst, int* __restrict__ counts, int e) {
    int i = blockIdx.x * 256 + threadIdx.x;
    if (i < e) atomicAdd(&counts[dst[i]], 1);
}

__global__ void dinv_kernel(const int* __restrict__ counts, float* __restrict__ dinv, int n) {
    int i = blockIdx.x * 256 + threadIdx.x;
    if (i < n) dinv[i] = rsqrtf((float)(counts[i] + 1));  // +1 self loop, deg>=1
}

// 3-kernel exclusive scan of counts -> row_ptr (N up to 256*2048)
__global__ void scan_part(const int* __restrict__ counts, int* __restrict__ partial, int n) {
    __shared__ int sm[256];
    int b = blockIdx.x, t = threadIdx.x;
    int base = b * 2048 + t * 8;
    int s = 0;
#pragma unroll
    for (int j = 0; j < 8; j++) { int idx = base + j; if (idx < n) s += counts[idx]; }
    sm[t] = s; __syncthreads();
    for (int off = 128; off > 0; off >>= 1) { if (t < off) sm[t] += sm[t + off]; __syncthreads(); }
    if (t == 0) partial[b] = sm[0];
}

__global__ void scan_top(int* partial, int nb) {
    __shared__ int sm[256];
    int t = threadIdx.x;
    int v = (t < nb) ? partial[t] : 0;
    sm[t] = v; __syncthreads();
    for (int off = 1; off < 256; off <<= 1) {
        int u = (t >= off) ? sm[t - off] : 0;
        __syncthreads();
        sm[t] += u;
        __syncthreads();
    }
    if (t < nb) partial[t] = sm[t] - v;  // exclusive
}

__global__ void scan_down(const int* __restrict__ counts, const int* __restrict__ blockoff,
                          int* __restrict__ row_ptr, int n) {
    __shared__ int sm[256];
    int b = blockIdx.x, t = threadIdx.x;
    int base = b * 2048 + t * 8;
    int c[8], local[8];
    int s = 0;
#pragma unroll
    for (int j = 0; j < 8; j++) {
        int idx = base + j;
        c[j] = (idx < n) ? counts[idx] : 0;
        local[j] = s; s += c[j];
    }
    sm[t] = s; __syncthreads();
    int own = s;
    for (int off = 1; off < 256; off <<= 1) {
        int u = (t >= off) ? sm[t - off] : 0;
        __syncthreads();
        sm[t] += u;
        __syncthreads();
    }
    int basev = blockoff[b] + sm[t] - own;
#pragma unroll
    for (int j = 0; j < 8; j++) { int idx = base + j; if (idx < n) row_ptr[idx] = basev + local[j]; }
}

__global__ void fill_kernel(const int* __restrict__ src, const int* __restrict__ dst,
                            const int* __restrict__ row_ptr, int* __restrict__ cursor,
                            int* __restrict__ csr_src, int e) {
    int i = blockIdx.x * 256 + threadIdx.x;
    if (i >= e) return;
    int s = src[i], d = dst[i];
    int pos = row_ptr[d] + atomicAdd(&cursor[d], 1);
    csr_src[pos] = s;
}

// ---------------- weight pack: fp32 W[128][128] -> split-bf16 MFMA B-fragment order ----
// For mfma_f32_16x16x32_bf16, lane = quad*16 + n holds B[c*32 + quad*8 + j][ntile*16 + n].
// Packed index: ((ntile*4 + kchunk)*64 + lane)*8 + j  (one 16B bf16x8 per lane per (nt,c)).

__global__ void pack_w(const float* __restrict__ W1, const float* __restrict__ W2,
                       __bf16* __restrict__ pw) {
    int t = blockIdx.x * 256 + threadIdx.x;  // 0..32767
    int which = t >> 14, idx = t & 16383;
    const float* W = which ? W2 : W1;
    float w = W[idx];
    __bf16 h = (__bf16)w;
    __bf16 l = (__bf16)(w - (float)h);
    int k = idx >> 7, n = idx & 127;
    int ntile = n >> 4, nl = n & 15;
    int kchunk = k >> 5, quad = (k >> 3) & 3, j = k & 7;
    int o = (((ntile * 4 + kchunk) * 64 + quad * 16 + nl) << 3) + j;
    __bf16* base = pw + (size_t)which * 32768;  // [w1hi|w1lo] then [w2hi|w2lo]
    base[o] = h;
    base[16384 + o] = l;
}

// ---------------- GEMM: Z[n,128] = X[n,128] @ W  via split-bf16 MFMA ----------------
// block = 256 threads = 4 waves; wave computes 32 rows x 128 cols (2 rowgroups of 16).
// Z = Xhi@Whi + Xlo@Whi + Xhi@Wlo  (error ~2^-16 relative).

__launch_bounds__(256, 2)
__global__ void gemm_mfma(const float* __restrict__ X, const __bf16* __restrict__ PW,
                          float* __restrict__ Z, int nrows) {
    int t = threadIdx.x;
    int wave = t >> 6, lane = t & 63;
    int qm = lane & 15, quad = lane >> 4;
    int r0 = blockIdx.x * 128 + wave * 32;

    // A fragments: lane holds X[row][c*32 + quad*8 + 0..7], row = r0 + rg*16 + qm
    bf16x8 ahi[2][4], alo[2][4];
#pragma unroll
    for (int rg = 0; rg < 2; rg++) {
        int row = r0 + rg * 16 + qm;
        bool valid = row < nrows;
        const float* xr = X + (size_t)row * D + quad * 8;
#pragma unroll
        for (int c = 0; c < 4; c++) {
            float4 zf = {0.f, 0.f, 0.f, 0.f};
            float4 xa = valid ? ((const float4*)(xr + c * 32))[0] : zf;
            float4 xb = valid ? ((const float4*)(xr + c * 32))[1] : zf;
            float xs[8] = {xa.x, xa.y, xa.z, xa.w, xb.x, xb.y, xb.z, xb.w};
            bf16x8 h, l;
#pragma unroll
            for (int j = 0; j < 8; j++) {
                float v = xs[j];
                __bf16 hh = (__bf16)v;
                h[j] = hh;
                l[j] = (__bf16)(v - (float)hh);
            }
            ahi[rg][c] = h; alo[rg][c] = l;
        }
    }

    f32x4 acc[2][8];
#pragma unroll
    for (int rg = 0; rg < 2; rg++)
#pragma unroll
        for (int nt = 0; nt < 8; nt++) acc[rg][nt] = (f32x4){0.f, 0.f, 0.f, 0.f};

    const bf16x8* Bh = (const bf16x8*)PW;            // hi
    const bf16x8* Bl = (const bf16x8*)(PW + 16384);  // lo

#pragma unroll
    for (int c = 0; c < 4; c++) {
        bf16x8 bh[8], bl[8];
#pragma unroll
        for (int nt = 0; nt < 8; nt++) {
            bh[nt] = Bh[(nt * 4 + c) * 64 + lane];
            bl[nt] = Bl[(nt * 4 + c) * 64 + lane];
        }
#pragma unroll
        for (int nt = 0; nt < 8; nt++) {
#pragma unroll
            for (int rg = 0; rg < 2; rg++) {
                acc[rg][nt] = __builtin_amdgcn_mfma_f32_16x16x32_bf16(ahi[rg][c], bh[nt], acc[rg][nt], 0, 0, 0);
                acc[rg][nt] = __builtin_amdgcn_mfma_f32_16x16x32_bf16(alo[rg][c], bh[nt], acc[rg][nt], 0, 0, 0);
                acc[rg][nt] = __builtin_amdgcn_mfma_f32_16x16x32_bf16(ahi[rg][c], bl[nt], acc[rg][nt], 0, 0, 0);
            }
        }
    }

    // C/D layout: col = lane&15, row = quad*4 + reg
#pragma unroll
    for (int rg = 0; rg < 2; rg++) {
        int rowb = r0 + rg * 16 + quad * 4;
#pragma unroll
        for (int reg = 0; reg < 4; reg++) {
            int row = rowb + reg;
            if (row < nrows) {
                float* zr = Z + (size_t)row * D + qm;
#pragma unroll
                for (int nt = 0; nt < 8; nt++) zr[nt * 16] = acc[rg][nt][reg];
            }
        }
    }
}

// ---------------- aggregation: h[v] = relu(dinv[v]^2*z[v] + sum dinv[s]*dinv[v]*z[s] + b) ----

__global__ void agg_kernel(const float4* __restrict__ z, const int* __restrict__ row_ptr,
                           const int* __restrict__ counts, const int* __restrict__ csr_src,
                           const float* __restrict__ dinv, const float* __restrict__ bias,
                           float4* __restrict__ h, int n) {
    int t = blockIdx.x * 256 + threadIdx.x;
    int v = t >> 5, f = t & 31;
    if (v >= n) return;
    float dv = dinv[v];
    float sw = dv * dv;
    float4 zc = z[(size_t)v * 32 + f];
    float4 acc;
    acc.x = zc.x * sw; acc.y = zc.y * sw; acc.z = zc.z * sw; acc.w = zc.w * sw;
    int start = row_ptr[v], cnt = counts[v];
    for (int i = 0; i < cnt; i++) {
        int s = csr_src[start + i];
        float w = dinv[s] * dv;
        float4 m = z[(size_t)s * 32 + f];
        acc.x = fmaf(w, m.x, acc.x);
        acc.y = fmaf(w, m.y, acc.y);
        acc.z = fmaf(w, m.z, acc.z);
        acc.w = fmaf(w, m.w, acc.w);
    }
    float4 bb = ((const float4*)bias)[f];
    acc.x = fmaxf(acc.x + bb.x, 0.f);
    acc.y = fmaxf(acc.y + bb.y, 0.f);
    acc.z = fmaxf(acc.z + bb.z, 0.f);
    acc.w = fmaxf(acc.w + bb.w, 0.f);
    h[(size_t)v * 32 + f] = acc;
}

// ---------------- FC: out[n,2] = h @ Wfc + bfc ----------------

__global__ void fc_kernel(const float4* __restrict__ h, const float* __restrict__ Wfc,
                          const float* __restrict__ bfc, float* __restrict__ out, int n) {
    int t = blockIdx.x * 256 + threadIdx.x;
    int v = t >> 5, f = t & 31;
    if (v >= n) return;
    float4 hv = h[(size_t)v * 32 + f];
    const float4* W4 = (const float4*)Wfc;
    float4 wa = W4[2 * f];
    float4 wb = W4[2 * f + 1];
    float a0 = hv.x * wa.x + hv.y * wa.z + hv.z * wb.x + hv.w * wb.z;
    float a1 = hv.x * wa.y + hv.y * wa.w + hv.z * wb.y + hv.w * wb.w;
    for (int off = 16; off > 0; off >>= 1) {
        a0 += __shfl_down(a0, off, 32);
        a1 += __shfl_down(a1, off, 32);
    }
    if (f == 0) {
        out[(size_t)v * 2 + 0] = a0 + bfc[0];
        out[(size_t)v * 2 + 1] = a1 + bfc[1];
    }
}

// ---------------- launch ----------------

extern "C" void kernel_launch(void* const* d_in, const int* in_sizes, int n_in,
                              void* d_out, int out_size, void* d_ws, size_t ws_size,
                              hipStream_t stream) {
    const float* x   = (const float*)d_in[0];
    const int*   ei  = (const int*)d_in[1];
    const float* W1  = (const float*)d_in[2];
    const float* b1  = (const float*)d_in[3];
    const float* W2  = (const float*)d_in[4];
    const float* b2  = (const float*)d_in[5];
    const float* Wfc = (const float*)d_in[6];
    const float* bfc = (const float*)d_in[7];
    float* out = (float*)d_out;

    int n = in_sizes[0] / D;   // 100000
    int e = in_sizes[1] / 2;   // 640000
    const int* src = ei;
    const int* dst = ei + e;

    // workspace layout (16B-aligned at these sizes)
    char* ws = (char*)d_ws;
    size_t nb = (size_t)n * 4;
    int*    counts  = (int*)(ws);
    int*    cursor  = (int*)(ws + nb);
    float*  dinv    = (float*)(ws + 2 * nb);
    int*    rowptr  = (int*)(ws + 3 * nb);
    int*    partial = (int*)(ws + 4 * nb);                     // 1024 B reserved
    int*    csr_src = (int*)(ws + 4 * nb + 1024);
    __bf16* pw      = (__bf16*)(ws + 4 * nb + 1024 + (size_t)e * 4);  // 4*32KB packed
    float*  bufA    = (float*)(ws + 4 * nb + 1024 + (size_t)e * 4 + 131072);
    float*  bufB    = bufA + (size_t)n * D;

    hipMemsetAsync(counts, 0, 2 * nb, stream);  // counts + cursor

    int eb = (e + 255) / 256;
    int sb = (n + 2047) / 2048;
    int gb = (n + 127) / 128;
    int ab = ((n * 32) + 255) / 256;

    count_kernel<<<eb, 256, 0, stream>>>(dst, counts, e);
    dinv_kernel<<<(n + 255) / 256, 256, 0, stream>>>(counts, dinv, n);
    scan_part<<<sb, 256, 0, stream>>>(counts, partial, n);
    scan_top<<<1, 256, 0, stream>>>(partial, sb);
    scan_down<<<sb, 256, 0, stream>>>(counts, partial, rowptr, n);
    fill_kernel<<<eb, 256, 0, stream>>>(src, dst, rowptr, cursor, csr_src, e);
    pack_w<<<128, 256, 0, stream>>>(W1, W2, pw);

    // layer 1
    gemm_mfma<<<gb, 256, 0, stream>>>(x, pw, bufA, n);
    agg_kernel<<<ab, 256, 0, stream>>>((const float4*)bufA, rowptr, counts, csr_src,
                                       dinv, b1, (float4*)bufB, n);
    // layer 2
    gemm_mfma<<<gb, 256, 0, stream>>>(bufB, pw + 32768, bufA, n);
    agg_kernel<<<ab, 256, 0, stream>>>((const float4*)bufA, rowptr, counts, csr_src,
                                       dinv, b2, (float4*)bufB, n);
    // classifier
    fc_kernel<<<ab, 256, 0, stream>>>((const float4*)bufB, Wfc, bfc, out, n);
}

// Round 4
// 368.968 us; speedup vs baseline: 1.1364x; 1.1364x over previous
//
#include <hip/hip_runtime.h>
#include <hip/hip_bf16.h>

#define D 128

typedef __bf16 bf16x4 __attribute__((ext_vector_type(4)));
typedef __bf16 bf16x8 __attribute__((ext_vector_type(8)));
typedef float f32x4 __attribute__((ext_vector_type(4)));

// stored col j  <->  true col PI(j) = (j&7)*16 + (j>>3);  PI_inv(c) = (c&15)*8 + (c>>4)
__device__ __host__ inline int PI(int j) { return ((j & 7) << 4) | (j >> 3); }

// ---------------- preprocessing ----------------

__global__ void count_kernel(const int* __restrict__ dst, int* __restrict__ counts, int e) {
    int i = blockIdx.x * 256 + threadIdx.x;
    if (i < e) atomicAdd(&counts[dst[i]], 1);
}

__global__ void dinv_kernel(const int* __restrict__ counts, float* __restrict__ dinv, int n) {
    int i = blockIdx.x * 256 + threadIdx.x;
    if (i < n) dinv[i] = rsqrtf((float)(counts[i] + 1));  // +1 self loop, deg>=1
}

// 3-kernel exclusive scan of counts -> row_ptr (N up to 256*2048)
__global__ void scan_part(const int* __restrict__ counts, int* __restrict__ partial, int n) {
    __shared__ int sm[256];
    int b = blockIdx.x, t = threadIdx.x;
    int base = b * 2048 + t * 8;
    int s = 0;
#pragma unroll
    for (int j = 0; j < 8; j++) { int idx = base + j; if (idx < n) s += counts[idx]; }
    sm[t] = s; __syncthreads();
    for (int off = 128; off > 0; off >>= 1) { if (t < off) sm[t] += sm[t + off]; __syncthreads(); }
    if (t == 0) partial[b] = sm[0];
}

__global__ void scan_top(int* partial, int nb) {
    __shared__ int sm[256];
    int t = threadIdx.x;
    int v = (t < nb) ? partial[t] : 0;
    sm[t] = v; __syncthreads();
    for (int off = 1; off < 256; off <<= 1) {
        int u = (t >= off) ? sm[t - off] : 0;
        __syncthreads();
        sm[t] += u;
        __syncthreads();
    }
    if (t < nb) partial[t] = sm[t] - v;  // exclusive
}

__global__ void scan_down(const int* __restrict__ counts, const int* __restrict__ blockoff,
                          int* __restrict__ row_ptr, int n) {
    __shared__ int sm[256];
    int b = blockIdx.x, t = threadIdx.x;
    int base = b * 2048 + t * 8;
    int c[8], local[8];
    int s = 0;
#pragma unroll
    for (int j = 0; j < 8; j++) {
        int idx = base + j;
        c[j] = (idx < n) ? counts[idx] : 0;
        local[j] = s; s += c[j];
    }
    sm[t] = s; __syncthreads();
    int own = s;
    for (int off = 1; off < 256; off <<= 1) {
        int u = (t >= off) ? sm[t - off] : 0;
        __syncthreads();
        sm[t] += u;
        __syncthreads();
    }
    int basev = blockoff[b] + sm[t] - own;
#pragma unroll
    for (int j = 0; j < 8; j++) { int idx = base + j; if (idx < n) row_ptr[idx] = basev + local[j]; }
}

__global__ void fill_kernel(const int* __restrict__ src, const int* __restrict__ dst,
                            const int* __restrict__ row_ptr, int* __restrict__ cursor,
                            int* __restrict__ csr_src, int e) {
    int i = blockIdx.x * 256 + threadIdx.x;
    if (i >= e) return;
    int s = src[i], d = dst[i];
    int pos = row_ptr[d] + atomicAdd(&cursor[d], 1);
    csr_src[pos] = s;
}

// ---------------- weight pack: fp32 W[128][128] -> split-bf16 MFMA B-fragment order ----
// Fragment slot (k_slot, n): lane quad*16+nl holds B[kchunk*32+quad*8+j][ntile*16+nl],
// packed at o = ((ntile*4+kchunk)*64 + quad*16 + nl)*8 + j.
// Layer 1: k_slot = k (A is x in true layout).
// Layer 2: k_slot = PI_inv(k) (A is h stored in PI-permuted cols).

__global__ void pack_w(const float* __restrict__ W1, const float* __restrict__ W2,
                       __bf16* __restrict__ pw) {
    int t = blockIdx.x * 256 + threadIdx.x;  // 0..32767
    int which = t >> 14, idx = t & 16383;
    const float* W = which ? W2 : W1;
    float w = W[idx];
    __bf16 h = (__bf16)w;
    __bf16 l = (__bf16)(w - (float)h);
    int k = idx >> 7, n = idx & 127;
    int ks = which ? (((k & 15) << 3) | (k >> 4)) : k;  // PI_inv for layer 2
    int ntile = n >> 4, nl = n & 15;
    int kchunk = ks >> 5, quad = (ks >> 3) & 3, j = ks & 7;
    int o = (((ntile * 4 + kchunk) * 64 + quad * 16 + nl) << 3) + j;
    __bf16* base = pw + (size_t)which * 32768;  // [w1hi|w1lo] then [w2hi|w2lo]
    base[o] = h;
    base[16384 + o] = l;
}

// ---------------- GEMM1: Zs[n,128] = X[n,128](fp32) @ W1, split-bf16 3-term ----------------
// 4 waves/block, 16 rows/wave, 64 rows/block. Output stored bf16, PI-permuted cols.

__global__ void gemm1_mfma(const float* __restrict__ X, const __bf16* __restrict__ PW,
                           __bf16* __restrict__ Zs, int nrows) {
    int t = threadIdx.x;
    int wave = t >> 6, lane = t & 63;
    int qm = lane & 15, quad = lane >> 4;
    int r0 = blockIdx.x * 64 + wave * 16;

    int row = r0 + qm;
    bool valid = row < nrows;
    const float* xr = X + (size_t)row * D + quad * 8;

    bf16x8 ahi[4], alo[4];
#pragma unroll
    for (int c = 0; c < 4; c++) {
        float4 zf = {0.f, 0.f, 0.f, 0.f};
        float4 xa = valid ? ((const float4*)(xr + c * 32))[0] : zf;
        float4 xb = valid ? ((const float4*)(xr + c * 32))[1] : zf;
        float xs[8] = {xa.x, xa.y, xa.z, xa.w, xb.x, xb.y, xb.z, xb.w};
        bf16x8 h, l;
#pragma unroll
        for (int j = 0; j < 8; j++) {
            float v = xs[j];
            __bf16 hh = (__bf16)v;
            h[j] = hh;
            l[j] = (__bf16)(v - (float)hh);
        }
        ahi[c] = h; alo[c] = l;
    }

    f32x4 acc[8];
#pragma unroll
    for (int nt = 0; nt < 8; nt++) acc[nt] = (f32x4){0.f, 0.f, 0.f, 0.f};

    const bf16x8* Bh = (const bf16x8*)PW;
    const bf16x8* Bl = (const bf16x8*)(PW + 16384);

#pragma unroll
    for (int c = 0; c < 4; c++) {
#pragma unroll
        for (int nt = 0; nt < 8; nt++) {
            bf16x8 bh = Bh[(nt * 4 + c) * 64 + lane];
            bf16x8 bl = Bl[(nt * 4 + c) * 64 + lane];
            acc[nt] = __builtin_amdgcn_mfma_f32_16x16x32_bf16(ahi[c], bh, acc[nt], 0, 0, 0);
            acc[nt] = __builtin_amdgcn_mfma_f32_16x16x32_bf16(alo[c], bh, acc[nt], 0, 0, 0);
            acc[nt] = __builtin_amdgcn_mfma_f32_16x16x32_bf16(ahi[c], bl, acc[nt], 0, 0, 0);
        }
    }

    // C/D: true col = nt*16+qm -> stored col qm*8+nt (contiguous per lane); row = quad*4+reg
#pragma unroll
    for (int reg = 0; reg < 4; reg++) {
        int orow = r0 + quad * 4 + reg;
        if (orow < nrows) {
            bf16x8 o;
#pragma unroll
            for (int nt = 0; nt < 8; nt++) o[nt] = (__bf16)acc[nt][reg];
            *(bf16x8*)(Zs + (size_t)orow * D + qm * 8) = o;
        }
    }
}

// ---------------- GEMM2: Zs2 = Hs[n,128](bf16, PI cols) @ W2, 2-term ----------------

__global__ void gemm2_mfma(const __bf16* __restrict__ Hs, const __bf16* __restrict__ PW,
                           __bf16* __restrict__ Zs, int nrows) {
    int t = threadIdx.x;
    int wave = t >> 6, lane = t & 63;
    int qm = lane & 15, quad = lane >> 4;
    int r0 = blockIdx.x * 64 + wave * 16;

    int row = r0 + qm;
    bool valid = row < nrows;
    const __bf16* hr = Hs + (size_t)row * D + quad * 8;

    bf16x8 a[4];
#pragma unroll
    for (int c = 0; c < 4; c++) {
        bf16x8 z8 = {};
        a[c] = valid ? *(const bf16x8*)(hr + c * 32) : z8;
    }

    f32x4 acc[8];
#pragma unroll
    for (int nt = 0; nt < 8; nt++) acc[nt] = (f32x4){0.f, 0.f, 0.f, 0.f};

    const bf16x8* Bh = (const bf16x8*)PW;
    const bf16x8* Bl = (const bf16x8*)(PW + 16384);

#pragma unroll
    for (int c = 0; c < 4; c++) {
#pragma unroll
        for (int nt = 0; nt < 8; nt++) {
            bf16x8 bh = Bh[(nt * 4 + c) * 64 + lane];
            bf16x8 bl = Bl[(nt * 4 + c) * 64 + lane];
            acc[nt] = __builtin_amdgcn_mfma_f32_16x16x32_bf16(a[c], bh, acc[nt], 0, 0, 0);
            acc[nt] = __builtin_amdgcn_mfma_f32_16x16x32_bf16(a[c], bl, acc[nt], 0, 0, 0);
        }
    }

#pragma unroll
    for (int reg = 0; reg < 4; reg++) {
        int orow = r0 + quad * 4 + reg;
        if (orow < nrows) {
            bf16x8 o;
#pragma unroll
            for (int nt = 0; nt < 8; nt++) o[nt] = (__bf16)acc[nt][reg];
            *(bf16x8*)(Zs + (size_t)orow * D + qm * 8) = o;
        }
    }
}

// ------- agg1: Hs[v] = relu(dinv^2*Zs[v] + sum dinv[s]*dinv[v]*Zs[s] + b1) (bf16 in/out) -------
// 32 lanes/node, 4 stored cols per lane (8 B gathers).

__global__ void agg1_kernel(const __bf16* __restrict__ Zs, const int* __restrict__ row_ptr,
                            const int* __restrict__ counts, const int* __restrict__ csr_src,
                            const float* __restrict__ dinv, const float* __restrict__ bias,
                            __bf16* __restrict__ Hs, int n) {
    int t = blockIdx.x * 256 + threadIdx.x;
    int v = t >> 5, f = t & 31;
    if (v >= n) return;
    float dv = dinv[v];
    float sw = dv * dv;
    bf16x4 zc = *(const bf16x4*)(Zs + (size_t)v * D + f * 4);
    float acc0 = (float)zc[0] * sw, acc1 = (float)zc[1] * sw;
    float acc2 = (float)zc[2] * sw, acc3 = (float)zc[3] * sw;
    int start = row_ptr[v], cnt = counts[v];
    for (int i = 0; i < cnt; i++) {
        int s = csr_src[start + i];
        float w = dinv[s] * dv;
        bf16x4 m = *(const bf16x4*)(Zs + (size_t)s * D + f * 4);
        acc0 = fmaf(w, (float)m[0], acc0);
        acc1 = fmaf(w, (float)m[1], acc1);
        acc2 = fmaf(w, (float)m[2], acc2);
        acc3 = fmaf(w, (float)m[3], acc3);
    }
    int j = f * 4;
    acc0 = fmaxf(acc0 + bias[PI(j + 0)], 0.f);
    acc1 = fmaxf(acc1 + bias[PI(j + 1)], 0.f);
    acc2 = fmaxf(acc2 + bias[PI(j + 2)], 0.f);
    acc3 = fmaxf(acc3 + bias[PI(j + 3)], 0.f);
    bf16x4 o = {(__bf16)acc0, (__bf16)acc1, (__bf16)acc2, (__bf16)acc3};
    *(bf16x4*)(Hs + (size_t)v * D + f * 4) = o;
}

// ------- agg2 + fc fused: out[v,2] = relu(agg(Zs2)) @ Wfc + bfc -------

__global__ void agg2_fc_kernel(const __bf16* __restrict__ Zs, const int* __restrict__ row_ptr,
                               const int* __restrict__ counts, const int* __restrict__ csr_src,
                               const float* __restrict__ dinv, const float* __restrict__ bias,
                               const float* __restrict__ Wfc, const float* __restrict__ bfc,
                               float* __restrict__ out, int n) {
    int t = blockIdx.x * 256 + threadIdx.x;
    int v = t >> 5, f = t & 31;
    if (v >= n) return;
    float dv = dinv[v];
    float sw = dv * dv;
    bf16x4 zc = *(const bf16x4*)(Zs + (size_t)v * D + f * 4);
    float acc0 = (float)zc[0] * sw, acc1 = (float)zc[1] * sw;
    float acc2 = (float)zc[2] * sw, acc3 = (float)zc[3] * sw;
    int start = row_ptr[v], cnt = counts[v];
    for (int i = 0; i < cnt; i++) {
        int s = csr_src[start + i];
        float w = dinv[s] * dv;
        bf16x4 m = *(const bf16x4*)(Zs + (size_t)s * D + f * 4);
        acc0 = fmaf(w, (float)m[0], acc0);
        acc1 = fmaf(w, (float)m[1], acc1);
        acc2 = fmaf(w, (float)m[2], acc2);
        acc3 = fmaf(w, (float)m[3], acc3);
    }
    int j = f * 4;
    int p0 = PI(j + 0), p1 = PI(j + 1), p2 = PI(j + 2), p3 = PI(j + 3);
    acc0 = fmaxf(acc0 + bias[p0], 0.f);
    acc1 = fmaxf(acc1 + bias[p1], 0.f);
    acc2 = fmaxf(acc2 + bias[p2], 0.f);
    acc3 = fmaxf(acc3 + bias[p3], 0.f);
    float a0 = acc0 * Wfc[p0 * 2] + acc1 * Wfc[p1 * 2] + acc2 * Wfc[p2 * 2] + acc3 * Wfc[p3 * 2];
    float a1 = acc0 * Wfc[p0 * 2 + 1] + acc1 * Wfc[p1 * 2 + 1] + acc2 * Wfc[p2 * 2 + 1] + acc3 * Wfc[p3 * 2 + 1];
    for (int off = 16; off > 0; off >>= 1) {
        a0 += __shfl_down(a0, off, 32);
        a1 += __shfl_down(a1, off, 32);
    }
    if (f == 0) {
        out[(size_t)v * 2 + 0] = a0 + bfc[0];
        out[(size_t)v * 2 + 1] = a1 + bfc[1];
    }
}

// ---------------- launch ----------------

extern "C" void kernel_launch(void* const* d_in, const int* in_sizes, int n_in,
                              void* d_out, int out_size, void* d_ws, size_t ws_size,
                              hipStream_t stream) {
    const float* x   = (const float*)d_in[0];
    const int*   ei  = (const int*)d_in[1];
    const float* W1  = (const float*)d_in[2];
    const float* b1  = (const float*)d_in[3];
    const float* W2  = (const float*)d_in[4];
    const float* b2  = (const float*)d_in[5];
    const float* Wfc = (const float*)d_in[6];
    const float* bfc = (const float*)d_in[7];
    float* out = (float*)d_out;

    int n = in_sizes[0] / D;   // 100000
    int e = in_sizes[1] / 2;   // 640000
    const int* src = ei;
    const int* dst = ei + e;

    // workspace layout (16B-aligned at these sizes)
    char* ws = (char*)d_ws;
    size_t nb = (size_t)n * 4;
    int*    counts  = (int*)(ws);
    int*    cursor  = (int*)(ws + nb);
    float*  dinv    = (float*)(ws + 2 * nb);
    int*    rowptr  = (int*)(ws + 3 * nb);
    int*    partial = (int*)(ws + 4 * nb);                     // 1024 B reserved
    int*    csr_src = (int*)(ws + 4 * nb + 1024);
    __bf16* pw      = (__bf16*)(ws + 4 * nb + 1024 + (size_t)e * 4);  // 128 KB packed
    __bf16* z1      = (__bf16*)(ws + 4 * nb + 1024 + (size_t)e * 4 + 131072);
    __bf16* h1      = z1 + (size_t)n * D;
    __bf16* z2      = h1 + (size_t)n * D;

    hipMemsetAsync(counts, 0, 2 * nb, stream);  // counts + cursor

    int eb = (e + 255) / 256;
    int sb = (n + 2047) / 2048;
    int gb = (n + 63) / 64;
    int ab = ((n * 32) + 255) / 256;

    count_kernel<<<eb, 256, 0, stream>>>(dst, counts, e);
    dinv_kernel<<<(n + 255) / 256, 256, 0, stream>>>(counts, dinv, n);
    scan_part<<<sb, 256, 0, stream>>>(counts, partial, n);
    scan_top<<<1, 256, 0, stream>>>(partial, sb);
    scan_down<<<sb, 256, 0, stream>>>(counts, partial, rowptr, n);
    fill_kernel<<<eb, 256, 0, stream>>>(src, dst, rowptr, cursor, csr_src, e);
    pack_w<<<128, 256, 0, stream>>>(W1, W2, pw);

    // layer 1
    gemm1_mfma<<<gb, 256, 0, stream>>>(x, pw, z1, n);
    agg1_kernel<<<ab, 256, 0, stream>>>(z1, rowptr, counts, csr_src, dinv, b1, h1, n);
    // layer 2
    gemm2_mfma<<<gb, 256, 0, stream>>>(h1, pw + 32768, z2, n);
    agg2_fc_kernel<<<ab, 256, 0, stream>>>(z2, rowptr, counts, csr_src, dinv, b2, Wfc, bfc, out, n);
}

// Round 5
// 276.366 us; speedup vs baseline: 1.5172x; 1.3351x over previous
//
#include <hip/hip_runtime.h>
#include <hip/hip_bf16.h>

#define D 128

typedef __bf16 bf16x8 __attribute__((ext_vector_type(8)));
typedef float f32x4 __attribute__((ext_vector_type(4)));

// stored col j  <->  true col PI(j) = (j&7)*16 + (j>>3);  PI_inv(c) = (c&15)*8 + (c>>4)

// ---------------- preprocessing ----------------

__global__ void count_kernel(const int* __restrict__ dst, int* __restrict__ counts, int e) {
    int i = blockIdx.x * 256 + threadIdx.x;
    if (i < e) atomicAdd(&counts[dst[i]], 1);
}

__global__ void dinv_kernel(const int* __restrict__ counts, float* __restrict__ dinv, int n) {
    int i = blockIdx.x * 256 + threadIdx.x;
    if (i < n) dinv[i] = rsqrtf((float)(counts[i] + 1));  // +1 self loop, deg>=1
}

// 3-kernel exclusive scan of counts -> row_ptr (N up to 256*2048)
__global__ void scan_part(const int* __restrict__ counts, int* __restrict__ partial, int n) {
    __shared__ int sm[256];
    int b = blockIdx.x, t = threadIdx.x;
    int base = b * 2048 + t * 8;
    int s = 0;
#pragma unroll
    for (int j = 0; j < 8; j++) { int idx = base + j; if (idx < n) s += counts[idx]; }
    sm[t] = s; __syncthreads();
    for (int off = 128; off > 0; off >>= 1) { if (t < off) sm[t] += sm[t + off]; __syncthreads(); }
    if (t == 0) partial[b] = sm[0];
}

__global__ void scan_top(int* partial, int nb) {
    __shared__ int sm[256];
    int t = threadIdx.x;
    int v = (t < nb) ? partial[t] : 0;
    sm[t] = v; __syncthreads();
    for (int off = 1; off < 256; off <<= 1) {
        int u = (t >= off) ? sm[t - off] : 0;
        __syncthreads();
        sm[t] += u;
        __syncthreads();
    }
    if (t < nb) partial[t] = sm[t] - v;  // exclusive
}

__global__ void scan_down(const int* __restrict__ counts, const int* __restrict__ blockoff,
                          int* __restrict__ row_ptr, int n) {
    __shared__ int sm[256];
    int b = blockIdx.x, t = threadIdx.x;
    int base = b * 2048 + t * 8;
    int c[8], local[8];
    int s = 0;
#pragma unroll
    for (int j = 0; j < 8; j++) {
        int idx = base + j;
        c[j] = (idx < n) ? counts[idx] : 0;
        local[j] = s; s += c[j];
    }
    sm[t] = s; __syncthreads();
    int own = s;
    for (int off = 1; off < 256; off <<= 1) {
        int u = (t >= off) ? sm[t - off] : 0;
        __syncthreads();
        sm[t] += u;
        __syncthreads();
    }
    int basev = blockoff[b] + sm[t] - own;
#pragma unroll
    for (int j = 0; j < 8; j++) { int idx = base + j; if (idx < n) row_ptr[idx] = basev + local[j]; }
}

__global__ void fill_kernel(const int* __restrict__ src, const int* __restrict__ dst,
                            const int* __restrict__ row_ptr, int* __restrict__ cursor,
                            int* __restrict__ csr_src, int e) {
    int i = blockIdx.x * 256 + threadIdx.x;
    if (i >= e) return;
    int s = src[i], d = dst[i];
    int pos = row_ptr[d] + atomicAdd(&cursor[d], 1);
    csr_src[pos] = s;
}

// ---------------- weight pack: fp32 W[128][128] -> bf16 MFMA B-fragment order ----
// Fragment slot (k_slot, n): lane quad*16+nl holds B[kchunk*32+quad*8+j][ntile*16+nl],
// packed at o = ((ntile*4+kchunk)*64 + quad*16 + nl)*8 + j.
// Layer 1: k_slot = k. Layer 2: k_slot = PI_inv(k) (A = h stored in PI-permuted cols).

__global__ void pack_w(const float* __restrict__ W1, const float* __restrict__ W2,
                       __bf16* __restrict__ pw) {
    int t = blockIdx.x * 256 + threadIdx.x;  // 0..32767
    int which = t >> 14, idx = t & 16383;
    const float* W = which ? W2 : W1;
    float w = W[idx];
    int k = idx >> 7, n = idx & 127;
    int ks = which ? (((k & 15) << 3) | (k >> 4)) : k;  // PI_inv for layer 2
    int ntile = n >> 4, nl = n & 15;
    int kchunk = ks >> 5, quad = (ks >> 3) & 3, j = ks & 7;
    int o = (((ntile * 4 + kchunk) * 64 + quad * 16 + nl) << 3) + j;
    pw[(size_t)which * 16384 + o] = (__bf16)w;
}

// ---------------- GEMM1: Zs = X(fp32) @ W1bf16, A split 2-term, B in LDS ----------------
// 4 waves/block, 16 rows/wave, 64 rows/block. Output bf16, PI-permuted cols.

__global__ void gemm1_mfma(const float* __restrict__ X, const __bf16* __restrict__ PW,
                           __bf16* __restrict__ Zs, int nrows) {
    __shared__ bf16x8 sB[2048];  // 32 KB packed W
    int t = threadIdx.x;
    const bf16x8* PW8 = (const bf16x8*)PW;
#pragma unroll
    for (int i = 0; i < 8; i++) sB[t + 256 * i] = PW8[t + 256 * i];

    int wave = t >> 6, lane = t & 63;
    int qm = lane & 15, quad = lane >> 4;
    int r0 = blockIdx.x * 64 + wave * 16;
    int row = r0 + qm;
    bool valid = row < nrows;
    const float* xr = X + (size_t)row * D + quad * 8;

    bf16x8 ahi[4], alo[4];
#pragma unroll
    for (int c = 0; c < 4; c++) {
        float4 zf = {0.f, 0.f, 0.f, 0.f};
        float4 xa = valid ? ((const float4*)(xr + c * 32))[0] : zf;
        float4 xb = valid ? ((const float4*)(xr + c * 32))[1] : zf;
        float xs[8] = {xa.x, xa.y, xa.z, xa.w, xb.x, xb.y, xb.z, xb.w};
        bf16x8 h, l;
#pragma unroll
        for (int j = 0; j < 8; j++) {
            float v = xs[j];
            __bf16 hh = (__bf16)v;
            h[j] = hh;
            l[j] = (__bf16)(v - (float)hh);
        }
        ahi[c] = h; alo[c] = l;
    }

    f32x4 acc[8];
#pragma unroll
    for (int nt = 0; nt < 8; nt++) acc[nt] = (f32x4){0.f, 0.f, 0.f, 0.f};

    __syncthreads();

#pragma unroll
    for (int c = 0; c < 4; c++) {
#pragma unroll
        for (int nt = 0; nt < 8; nt++) {
            bf16x8 b = sB[(nt * 4 + c) * 64 + lane];
            acc[nt] = __builtin_amdgcn_mfma_f32_16x16x32_bf16(ahi[c], b, acc[nt], 0, 0, 0);
            acc[nt] = __builtin_amdgcn_mfma_f32_16x16x32_bf16(alo[c], b, acc[nt], 0, 0, 0);
        }
    }

    // C/D: true col = nt*16+qm -> stored col qm*8+nt (contiguous); row = quad*4+reg
#pragma unroll
    for (int reg = 0; reg < 4; reg++) {
        int orow = r0 + quad * 4 + reg;
        if (orow < nrows) {
            bf16x8 o;
#pragma unroll
            for (int nt = 0; nt < 8; nt++) o[nt] = (__bf16)acc[nt][reg];
            *(bf16x8*)(Zs + (size_t)orow * D + qm * 8) = o;
        }
    }
}

// ---------------- GEMM2: Zs2 = Hs(bf16, PI cols) @ W2bf16, 1-term, B in LDS ----------------

__global__ void gemm2_mfma(const __bf16* __restrict__ Hs, const __bf16* __restrict__ PW,
                           __bf16* __restrict__ Zs, int nrows) {
    __shared__ bf16x8 sB[2048];  // 32 KB
    int t = threadIdx.x;
    const bf16x8* PW8 = (const bf16x8*)PW;
#pragma unroll
    for (int i = 0; i < 8; i++) sB[t + 256 * i] = PW8[t + 256 * i];

    int wave = t >> 6, lane = t & 63;
    int qm = lane & 15, quad = lane >> 4;
    int r0 = blockIdx.x * 64 + wave * 16;
    int row = r0 + qm;
    bool valid = row < nrows;
    const __bf16* hr = Hs + (size_t)row * D + quad * 8;

    bf16x8 a[4];
#pragma unroll
    for (int c = 0; c < 4; c++) {
        bf16x8 z8 = {};
        a[c] = valid ? *(const bf16x8*)(hr + c * 32) : z8;
    }

    f32x4 acc[8];
#pragma unroll
    for (int nt = 0; nt < 8; nt++) acc[nt] = (f32x4){0.f, 0.f, 0.f, 0.f};

    __syncthreads();

#pragma unroll
    for (int c = 0; c < 4; c++) {
#pragma unroll
        for (int nt = 0; nt < 8; nt++) {
            bf16x8 b = sB[(nt * 4 + c) * 64 + lane];
            acc[nt] = __builtin_amdgcn_mfma_f32_16x16x32_bf16(a[c], b, acc[nt], 0, 0, 0);
        }
    }

#pragma unroll
    for (int reg = 0; reg < 4; reg++) {
        int orow = r0 + quad * 4 + reg;
        if (orow < nrows) {
            bf16x8 o;
#pragma unroll
            for (int nt = 0; nt < 8; nt++) o[nt] = (__bf16)acc[nt][reg];
            *(bf16x8*)(Zs + (size_t)orow * D + qm * 8) = o;
        }
    }
}

// ------- agg1: Hs[v] = relu(dinv^2*Zs[v] + sum dinv[s]*dinv[v]*Zs[s] + b1) -------
// 16 lanes/node, bf16x8 (16B) gathers, 2x edge unroll for MLP.

__global__ void agg1_kernel(const __bf16* __restrict__ Zs, const int* __restrict__ row_ptr,
                            const int* __restrict__ counts, const int* __restrict__ csr_src,
                            const float* __restrict__ dinv, const float* __restrict__ bias,
                            __bf16* __restrict__ Hs, int n) {
    int t = blockIdx.x * 256 + threadIdx.x;
    int v = t >> 4, c = t & 15;
    if (v >= n) return;
    float dv = dinv[v];
    const bf16x8* Z8 = (const bf16x8*)Zs;  // row stride 16 chunks
    bf16x8 zc = Z8[(size_t)v * 16 + c];
    float sw = dv * dv;
    float acc[8];
#pragma unroll
    for (int j = 0; j < 8; j++) acc[j] = (float)zc[j] * sw;
    int start = row_ptr[v], cnt = counts[v];
    int i = 0;
    for (; i + 2 <= cnt; i += 2) {
        int s0 = csr_src[start + i], s1 = csr_src[start + i + 1];
        float w0 = dinv[s0] * dv, w1 = dinv[s1] * dv;
        bf16x8 m0 = Z8[(size_t)s0 * 16 + c];
        bf16x8 m1 = Z8[(size_t)s1 * 16 + c];
#pragma unroll
        for (int j = 0; j < 8; j++) acc[j] = fmaf(w0, (float)m0[j], acc[j]);
#pragma unroll
        for (int j = 0; j < 8; j++) acc[j] = fmaf(w1, (float)m1[j], acc[j]);
    }
    if (i < cnt) {
        int s0 = csr_src[start + i];
        float w0 = dinv[s0] * dv;
        bf16x8 m0 = Z8[(size_t)s0 * 16 + c];
#pragma unroll
        for (int j = 0; j < 8; j++) acc[j] = fmaf(w0, (float)m0[j], acc[j]);
    }
    bf16x8 o;
#pragma unroll
    for (int j = 0; j < 8; j++) o[j] = (__bf16)fmaxf(acc[j] + bias[j * 16 + c], 0.f);
    ((bf16x8*)Hs)[(size_t)v * 16 + c] = o;
}

// ------- agg2 + fc fused: out[v,2] = relu(agg(Zs2) + b2) @ Wfc + bfc -------

__global__ void agg2_fc_kernel(const __bf16* __restrict__ Zs, const int* __restrict__ row_ptr,
                               const int* __restrict__ counts, const int* __restrict__ csr_src,
                               const float* __restrict__ dinv, const float* __restrict__ bias,
                               const float* __restrict__ Wfc, const float* __restrict__ bfc,
                               float* __restrict__ out, int n) {
    int t = blockIdx.x * 256 + threadIdx.x;
    int v = t >> 4, c = t & 15;
    if (v >= n) return;
    float dv = dinv[v];
    const bf16x8* Z8 = (const bf16x8*)Zs;
    bf16x8 zc = Z8[(size_t)v * 16 + c];
    float sw = dv * dv;
    float acc[8];
#pragma unroll
    for (int j = 0; j < 8; j++) acc[j] = (float)zc[j] * sw;
    int start = row_ptr[v], cnt = counts[v];
    int i = 0;
    for (; i + 2 <= cnt; i += 2) {
        int s0 = csr_src[start + i], s1 = csr_src[start + i + 1];
        float w0 = dinv[s0] * dv, w1 = dinv[s1] * dv;
        bf16x8 m0 = Z8[(size_t)s0 * 16 + c];
        bf16x8 m1 = Z8[(size_t)s1 * 16 + c];
#pragma unroll
        for (int j = 0; j < 8; j++) acc[j] = fmaf(w0, (float)m0[j], acc[j]);
#pragma unroll
        for (int j = 0; j < 8; j++) acc[j] = fmaf(w1, (float)m1[j], acc[j]);
    }
    if (i < cnt) {
        int s0 = csr_src[start + i];
        float w0 = dinv[s0] * dv;
        bf16x8 m0 = Z8[(size_t)s0 * 16 + c];
#pragma unroll
        for (int j = 0; j < 8; j++) acc[j] = fmaf(w0, (float)m0[j], acc[j]);
    }
    float a0 = 0.f, a1 = 0.f;
#pragma unroll
    for (int j = 0; j < 8; j++) {
        int p = j * 16 + c;  // true col
        float hj = fmaxf(acc[j] + bias[p], 0.f);
        a0 = fmaf(hj, Wfc[p * 2], a0);
        a1 = fmaf(hj, Wfc[p * 2 + 1], a1);
    }
#pragma unroll
    for (int off = 8; off > 0; off >>= 1) {
        a0 += __shfl_down(a0, off, 16);
        a1 += __shfl_down(a1, off, 16);
    }
    if (c == 0) {
        out[(size_t)v * 2 + 0] = a0 + bfc[0];
        out[(size_t)v * 2 + 1] = a1 + bfc[1];
    }
}

// ---------------- launch ----------------

extern "C" void kernel_launch(void* const* d_in, const int* in_sizes, int n_in,
                              void* d_out, int out_size, void* d_ws, size_t ws_size,
                              hipStream_t stream) {
    const float* x   = (const float*)d_in[0];
    const int*   ei  = (const int*)d_in[1];
    const float* W1  = (const float*)d_in[2];
    const float* b1  = (const float*)d_in[3];
    const float* W2  = (const float*)d_in[4];
    const float* b2  = (const float*)d_in[5];
    const float* Wfc = (const float*)d_in[6];
    const float* bfc = (const float*)d_in[7];
    float* out = (float*)d_out;

    int n = in_sizes[0] / D;   // 100000
    int e = in_sizes[1] / 2;   // 640000
    const int* src = ei;
    const int* dst = ei + e;

    // workspace layout (16B-aligned at these sizes)
    char* ws = (char*)d_ws;
    size_t nb = (size_t)n * 4;
    int*    counts  = (int*)(ws);
    int*    cursor  = (int*)(ws + nb);
    float*  dinv    = (float*)(ws + 2 * nb);
    int*    rowptr  = (int*)(ws + 3 * nb);
    int*    partial = (int*)(ws + 4 * nb);                     // 1024 B reserved
    int*    csr_src = (int*)(ws + 4 * nb + 1024);
    __bf16* pw      = (__bf16*)(ws + 4 * nb + 1024 + (size_t)e * 4);  // 64 KB packed (W1|W2)
    __bf16* z1      = (__bf16*)(ws + 4 * nb + 1024 + (size_t)e * 4 + 65536);
    __bf16* h1      = z1 + (size_t)n * D;
    __bf16* z2      = h1 + (size_t)n * D;

    hipMemsetAsync(counts, 0, 2 * nb, stream);  // counts + cursor

    int eb = (e + 255) / 256;
    int sb = (n + 2047) / 2048;
    int gb = (n + 63) / 64;
    int ab = ((n * 16) + 255) / 256;

    count_kernel<<<eb, 256, 0, stream>>>(dst, counts, e);
    dinv_kernel<<<(n + 255) / 256, 256, 0, stream>>>(counts, dinv, n);
    scan_part<<<sb, 256, 0, stream>>>(counts, partial, n);
    scan_top<<<1, 256, 0, stream>>>(partial, sb);
    scan_down<<<sb, 256, 0, stream>>>(counts, partial, rowptr, n);
    fill_kernel<<<eb, 256, 0, stream>>>(src, dst, rowptr, cursor, csr_src, e);
    pack_w<<<128, 256, 0, stream>>>(W1, W2, pw);

    // layer 1
    gemm1_mfma<<<gb, 256, 0, stream>>>(x, pw, z1, n);
    agg1_kernel<<<ab, 256, 0, stream>>>(z1, rowptr, counts, csr_src, dinv, b1, h1, n);
    // layer 2
    gemm2_mfma<<<gb, 256, 0, stream>>>(h1, pw + 16384, z2, n);
    agg2_fc_kernel<<<ab, 256, 0, stream>>>(z2, rowptr, counts, csr_src, dinv, b2, Wfc, bfc, out, n);
}

// Round 6
// 251.258 us; speedup vs baseline: 1.6688x; 1.0999x over previous
//
#include <hip/hip_runtime.h>
#include <hip/hip_bf16.h>

#define D 128

typedef __bf16 bf16x8 __attribute__((ext_vector_type(8)));
typedef float f32x4 __attribute__((ext_vector_type(4)));

// stored col j  <->  true col PI(j) = (j&7)*16 + (j>>3);  PI_inv(c) = (c&15)*8 + (c>>4)

// ---------------- preprocessing ----------------

// counts in-degree AND records each edge's slot within its dst bucket (coalesced).
__global__ void count_kernel(const int* __restrict__ dst, int* __restrict__ counts,
                             int* __restrict__ eoff, int e) {
    int i0 = (blockIdx.x * 256 + threadIdx.x) * 4;
    if (i0 + 4 <= e) {
        int4 d4 = *(const int4*)(dst + i0);
        int4 o;
        o.x = atomicAdd(&counts[d4.x], 1);
        o.y = atomicAdd(&counts[d4.y], 1);
        o.z = atomicAdd(&counts[d4.z], 1);
        o.w = atomicAdd(&counts[d4.w], 1);
        *(int4*)(eoff + i0) = o;
    } else {
        for (int i = i0; i < e; i++) eoff[i] = atomicAdd(&counts[dst[i]], 1);
    }
}

__global__ void dinv_kernel(const int* __restrict__ counts, float* __restrict__ dinv, int n) {
    int i = blockIdx.x * 256 + threadIdx.x;
    if (i < n) dinv[i] = rsqrtf((float)(counts[i] + 1));  // +1 self loop, deg>=1
}

// 3-kernel exclusive scan of counts -> row_ptr (N up to 256*2048)
__global__ void scan_part(const int* __restrict__ counts, int* __restrict__ partial, int n) {
    __shared__ int sm[256];
    int b = blockIdx.x, t = threadIdx.x;
    int base = b * 2048 + t * 8;
    int s = 0;
#pragma unroll
    for (int j = 0; j < 8; j++) { int idx = base + j; if (idx < n) s += counts[idx]; }
    sm[t] = s; __syncthreads();
    for (int off = 128; off > 0; off >>= 1) { if (t < off) sm[t] += sm[t + off]; __syncthreads(); }
    if (t == 0) partial[b] = sm[0];
}

__global__ void scan_top(int* partial, int nb) {
    __shared__ int sm[256];
    int t = threadIdx.x;
    int v = (t < nb) ? partial[t] : 0;
    sm[t] = v; __syncthreads();
    for (int off = 1; off < 256; off <<= 1) {
        int u = (t >= off) ? sm[t - off] : 0;
        __syncthreads();
        sm[t] += u;
        __syncthreads();
    }
    if (t < nb) partial[t] = sm[t] - v;  // exclusive
}

__global__ void scan_down(const int* __restrict__ counts, const int* __restrict__ blockoff,
                          int* __restrict__ row_ptr, int n) {
    __shared__ int sm[256];
    int b = blockIdx.x, t = threadIdx.x;
    int base = b * 2048 + t * 8;
    int c[8], local[8];
    int s = 0;
#pragma unroll
    for (int j = 0; j < 8; j++) {
        int idx = base + j;
        c[j] = (idx < n) ? counts[idx] : 0;
        local[j] = s; s += c[j];
    }
    sm[t] = s; __syncthreads();
    int own = s;
    for (int off = 1; off < 256; off <<= 1) {
        int u = (t >= off) ? sm[t - off] : 0;
        __syncthreads();
        sm[t] += u;
        __syncthreads();
    }
    int basev = blockoff[b] + sm[t] - own;
#pragma unroll
    for (int j = 0; j < 8; j++) { int idx = base + j; if (idx < n) row_ptr[idx] = basev + local[j]; }
}

// no atomics: slot was captured during count. Entry packs {src, norm}.
__global__ void fill_kernel(const int* __restrict__ src, const int* __restrict__ dst,
                            const int* __restrict__ row_ptr, const int* __restrict__ eoff,
                            const float* __restrict__ dinv, int2* __restrict__ csr, int e) {
    int i0 = (blockIdx.x * 256 + threadIdx.x) * 4;
    if (i0 + 4 <= e) {
        int4 s4 = *(const int4*)(src + i0);
        int4 d4 = *(const int4*)(dst + i0);
        int4 o4 = *(const int4*)(eoff + i0);
        int p0 = row_ptr[d4.x] + o4.x;
        int p1 = row_ptr[d4.y] + o4.y;
        int p2 = row_ptr[d4.z] + o4.z;
        int p3 = row_ptr[d4.w] + o4.w;
        float w0 = dinv[s4.x] * dinv[d4.x];
        float w1 = dinv[s4.y] * dinv[d4.y];
        float w2 = dinv[s4.z] * dinv[d4.z];
        float w3 = dinv[s4.w] * dinv[d4.w];
        csr[p0] = make_int2(s4.x, __float_as_int(w0));
        csr[p1] = make_int2(s4.y, __float_as_int(w1));
        csr[p2] = make_int2(s4.z, __float_as_int(w2));
        csr[p3] = make_int2(s4.w, __float_as_int(w3));
    } else {
        for (int i = i0; i < e; i++) {
            int s = src[i], d = dst[i];
            int pos = row_ptr[d] + eoff[i];
            csr[pos] = make_int2(s, __float_as_int(dinv[s] * dinv[d]));
        }
    }
}

// ---------------- weight pack: fp32 W[128][128] -> bf16 MFMA B-fragment order ----
// Fragment slot (k_slot, n): lane quad*16+nl holds B[kchunk*32+quad*8+j][ntile*16+nl],
// packed at o = ((ntile*4+kchunk)*64 + quad*16 + nl)*8 + j.
// Layer 1: k_slot = k. Layer 2: k_slot = PI_inv(k) (A = h stored in PI-permuted cols).

__global__ void pack_w(const float* __restrict__ W1, const float* __restrict__ W2,
                       __bf16* __restrict__ pw) {
    int t = blockIdx.x * 256 + threadIdx.x;  // 0..32767
    int which = t >> 14, idx = t & 16383;
    const float* W = which ? W2 : W1;
    float w = W[idx];
    int k = idx >> 7, n = idx & 127;
    int ks = which ? (((k & 15) << 3) | (k >> 4)) : k;  // PI_inv for layer 2
    int ntile = n >> 4, nl = n & 15;
    int kchunk = ks >> 5, quad = (ks >> 3) & 3, j = ks & 7;
    int o = (((ntile * 4 + kchunk) * 64 + quad * 16 + nl) << 3) + j;
    pw[(size_t)which * 16384 + o] = (__bf16)w;
}

// ---------------- GEMM1: Zs = X(fp32) @ W1bf16, A split 2-term, B in LDS ----------------
// 4 waves/block, 16 rows/wave, 64 rows/block. Output bf16, PI-permuted cols.

__global__ void gemm1_mfma(const float* __restrict__ X, const __bf16* __restrict__ PW,
                           __bf16* __restrict__ Zs, int nrows) {
    __shared__ bf16x8 sB[2048];  // 32 KB packed W
    int t = threadIdx.x;
    const bf16x8* PW8 = (const bf16x8*)PW;
#pragma unroll
    for (int i = 0; i < 8; i++) sB[t + 256 * i] = PW8[t + 256 * i];

    int wave = t >> 6, lane = t & 63;
    int qm = lane & 15, quad = lane >> 4;
    int r0 = blockIdx.x * 64 + wave * 16;
    int row = r0 + qm;
    bool valid = row < nrows;
    const float* xr = X + (size_t)row * D + quad * 8;

    bf16x8 ahi[4], alo[4];
#pragma unroll
    for (int c = 0; c < 4; c++) {
        float4 zf = {0.f, 0.f, 0.f, 0.f};
        float4 xa = valid ? ((const float4*)(xr + c * 32))[0] : zf;
        float4 xb = valid ? ((const float4*)(xr + c * 32))[1] : zf;
        float xs[8] = {xa.x, xa.y, xa.z, xa.w, xb.x, xb.y, xb.z, xb.w};
        bf16x8 h, l;
#pragma unroll
        for (int j = 0; j < 8; j++) {
            float v = xs[j];
            __bf16 hh = (__bf16)v;
            h[j] = hh;
            l[j] = (__bf16)(v - (float)hh);
        }
        ahi[c] = h; alo[c] = l;
    }

    f32x4 acc[8];
#pragma unroll
    for (int nt = 0; nt < 8; nt++) acc[nt] = (f32x4){0.f, 0.f, 0.f, 0.f};

    __syncthreads();

#pragma unroll
    for (int c = 0; c < 4; c++) {
#pragma unroll
        for (int nt = 0; nt < 8; nt++) {
            bf16x8 b = sB[(nt * 4 + c) * 64 + lane];
            acc[nt] = __builtin_amdgcn_mfma_f32_16x16x32_bf16(ahi[c], b, acc[nt], 0, 0, 0);
            acc[nt] = __builtin_amdgcn_mfma_f32_16x16x32_bf16(alo[c], b, acc[nt], 0, 0, 0);
        }
    }

    // C/D: true col = nt*16+qm -> stored col qm*8+nt (contiguous); row = quad*4+reg
#pragma unroll
    for (int reg = 0; reg < 4; reg++) {
        int orow = r0 + quad * 4 + reg;
        if (orow < nrows) {
            bf16x8 o;
#pragma unroll
            for (int nt = 0; nt < 8; nt++) o[nt] = (__bf16)acc[nt][reg];
            *(bf16x8*)(Zs + (size_t)orow * D + qm * 8) = o;
        }
    }
}

// ---------------- GEMM2: Zs2 = Hs(bf16, PI cols) @ W2bf16, 1-term, B in LDS ----------------

__global__ void gemm2_mfma(const __bf16* __restrict__ Hs, const __bf16* __restrict__ PW,
                           __bf16* __restrict__ Zs, int nrows) {
    __shared__ bf16x8 sB[2048];  // 32 KB
    int t = threadIdx.x;
    const bf16x8* PW8 = (const bf16x8*)PW;
#pragma unroll
    for (int i = 0; i < 8; i++) sB[t + 256 * i] = PW8[t + 256 * i];

    int wave = t >> 6, lane = t & 63;
    int qm = lane & 15, quad = lane >> 4;
    int r0 = blockIdx.x * 64 + wave * 16;
    int row = r0 + qm;
    bool valid = row < nrows;
    const __bf16* hr = Hs + (size_t)row * D + quad * 8;

    bf16x8 a[4];
#pragma unroll
    for (int c = 0; c < 4; c++) {
        bf16x8 z8 = {};
        a[c] = valid ? *(const bf16x8*)(hr + c * 32) : z8;
    }

    f32x4 acc[8];
#pragma unroll
    for (int nt = 0; nt < 8; nt++) acc[nt] = (f32x4){0.f, 0.f, 0.f, 0.f};

    __syncthreads();

#pragma unroll
    for (int c = 0; c < 4; c++) {
#pragma unroll
        for (int nt = 0; nt < 8; nt++) {
            bf16x8 b = sB[(nt * 4 + c) * 64 + lane];
            acc[nt] = __builtin_amdgcn_mfma_f32_16x16x32_bf16(a[c], b, acc[nt], 0, 0, 0);
        }
    }

#pragma unroll
    for (int reg = 0; reg < 4; reg++) {
        int orow = r0 + quad * 4 + reg;
        if (orow < nrows) {
            bf16x8 o;
#pragma unroll
            for (int nt = 0; nt < 8; nt++) o[nt] = (__bf16)acc[nt][reg];
            *(bf16x8*)(Zs + (size_t)orow * D + qm * 8) = o;
        }
    }
}

// ------- agg1: Hs[v] = relu(dinv^2*Zs[v] + sum w*Zs[s] + b1) -------
// 16 lanes/node, bf16x8 (16B) gathers, 4x edge unroll; csr entry = {src, norm}.

__global__ void agg1_kernel(const __bf16* __restrict__ Zs, const int* __restrict__ row_ptr,
                            const int* __restrict__ counts, const int2* __restrict__ csr,
                            const float* __restrict__ dinv, const float* __restrict__ bias,
                            __bf16* __restrict__ Hs, int n) {
    int t = blockIdx.x * 256 + threadIdx.x;
    int v = t >> 4, c = t & 15;
    if (v >= n) return;
    float dv = dinv[v];
    const bf16x8* Z8 = (const bf16x8*)Zs;  // row stride 16 chunks
    bf16x8 zc = Z8[(size_t)v * 16 + c];
    float sw = dv * dv;
    float acc[8];
#pragma unroll
    for (int j = 0; j < 8; j++) acc[j] = (float)zc[j] * sw;
    int start = row_ptr[v], cnt = counts[v];
    int i = 0;
    for (; i + 4 <= cnt; i += 4) {
        int2 e0 = csr[start + i], e1 = csr[start + i + 1];
        int2 e2 = csr[start + i + 2], e3 = csr[start + i + 3];
        bf16x8 m0 = Z8[(size_t)e0.x * 16 + c];
        bf16x8 m1 = Z8[(size_t)e1.x * 16 + c];
        bf16x8 m2 = Z8[(size_t)e2.x * 16 + c];
        bf16x8 m3 = Z8[(size_t)e3.x * 16 + c];
        float w0 = __int_as_float(e0.y), w1 = __int_as_float(e1.y);
        float w2 = __int_as_float(e2.y), w3 = __int_as_float(e3.y);
#pragma unroll
        for (int j = 0; j < 8; j++) acc[j] = fmaf(w0, (float)m0[j], acc[j]);
#pragma unroll
        for (int j = 0; j < 8; j++) acc[j] = fmaf(w1, (float)m1[j], acc[j]);
#pragma unroll
        for (int j = 0; j < 8; j++) acc[j] = fmaf(w2, (float)m2[j], acc[j]);
#pragma unroll
        for (int j = 0; j < 8; j++) acc[j] = fmaf(w3, (float)m3[j], acc[j]);
    }
    for (; i < cnt; i++) {
        int2 e0 = csr[start + i];
        float w0 = __int_as_float(e0.y);
        bf16x8 m0 = Z8[(size_t)e0.x * 16 + c];
#pragma unroll
        for (int j = 0; j < 8; j++) acc[j] = fmaf(w0, (float)m0[j], acc[j]);
    }
    bf16x8 o;
#pragma unroll
    for (int j = 0; j < 8; j++) o[j] = (__bf16)fmaxf(acc[j] + bias[j * 16 + c], 0.f);
    ((bf16x8*)Hs)[(size_t)v * 16 + c] = o;
}

// ------- agg2 + fc fused: out[v,2] = relu(agg(Zs2) + b2) @ Wfc + bfc -------

__global__ void agg2_fc_kernel(const __bf16* __restrict__ Zs, const int* __restrict__ row_ptr,
                               const int* __restrict__ counts, const int2* __restrict__ csr,
                               const float* __restrict__ dinv, const float* __restrict__ bias,
                               const float* __restrict__ Wfc, const float* __restrict__ bfc,
                               float* __restrict__ out, int n) {
    int t = blockIdx.x * 256 + threadIdx.x;
    int v = t >> 4, c = t & 15;
    if (v >= n) return;
    float dv = dinv[v];
    const bf16x8* Z8 = (const bf16x8*)Zs;
    bf16x8 zc = Z8[(size_t)v * 16 + c];
    float sw = dv * dv;
    float acc[8];
#pragma unroll
    for (int j = 0; j < 8; j++) acc[j] = (float)zc[j] * sw;
    int start = row_ptr[v], cnt = counts[v];
    int i = 0;
    for (; i + 4 <= cnt; i += 4) {
        int2 e0 = csr[start + i], e1 = csr[start + i + 1];
        int2 e2 = csr[start + i + 2], e3 = csr[start + i + 3];
        bf16x8 m0 = Z8[(size_t)e0.x * 16 + c];
        bf16x8 m1 = Z8[(size_t)e1.x * 16 + c];
        bf16x8 m2 = Z8[(size_t)e2.x * 16 + c];
        bf16x8 m3 = Z8[(size_t)e3.x * 16 + c];
        float w0 = __int_as_float(e0.y), w1 = __int_as_float(e1.y);
        float w2 = __int_as_float(e2.y), w3 = __int_as_float(e3.y);
#pragma unroll
        for (int j = 0; j < 8; j++) acc[j] = fmaf(w0, (float)m0[j], acc[j]);
#pragma unroll
        for (int j = 0; j < 8; j++) acc[j] = fmaf(w1, (float)m1[j], acc[j]);
#pragma unroll
        for (int j = 0; j < 8; j++) acc[j] = fmaf(w2, (float)m2[j], acc[j]);
#pragma unroll
        for (int j = 0; j < 8; j++) acc[j] = fmaf(w3, (float)m3[j], acc[j]);
    }
    for (; i < cnt; i++) {
        int2 e0 = csr[start + i];
        float w0 = __int_as_float(e0.y);
        bf16x8 m0 = Z8[(size_t)e0.x * 16 + c];
#pragma unroll
        for (int j = 0; j < 8; j++) acc[j] = fmaf(w0, (float)m0[j], acc[j]);
    }
    float a0 = 0.f, a1 = 0.f;
#pragma unroll
    for (int j = 0; j < 8; j++) {
        int p = j * 16 + c;  // true col
        float hj = fmaxf(acc[j] + bias[p], 0.f);
        a0 = fmaf(hj, Wfc[p * 2], a0);
        a1 = fmaf(hj, Wfc[p * 2 + 1], a1);
    }
#pragma unroll
    for (int off = 8; off > 0; off >>= 1) {
        a0 += __shfl_down(a0, off, 16);
        a1 += __shfl_down(a1, off, 16);
    }
    if (c == 0) {
        out[(size_t)v * 2 + 0] = a0 + bfc[0];
        out[(size_t)v * 2 + 1] = a1 + bfc[1];
    }
}

// ---------------- launch ----------------

extern "C" void kernel_launch(void* const* d_in, const int* in_sizes, int n_in,
                              void* d_out, int out_size, void* d_ws, size_t ws_size,
                              hipStream_t stream) {
    const float* x   = (const float*)d_in[0];
    const int*   ei  = (const int*)d_in[1];
    const float* W1  = (const float*)d_in[2];
    const float* b1  = (const float*)d_in[3];
    const float* W2  = (const float*)d_in[4];
    const float* b2  = (const float*)d_in[5];
    const float* Wfc = (const float*)d_in[6];
    const float* bfc = (const float*)d_in[7];
    float* out = (float*)d_out;

    int n = in_sizes[0] / D;   // 100000
    int e = in_sizes[1] / 2;   // 640000
    const int* src = ei;
    const int* dst = ei + e;

    // workspace layout (16B-aligned at these sizes)
    char* ws = (char*)d_ws;
    size_t nb = (size_t)n * 4;
    int*    counts  = (int*)(ws);
    float*  dinv    = (float*)(ws + nb);
    int*    rowptr  = (int*)(ws + 2 * nb);
    int*    partial = (int*)(ws + 3 * nb);                     // 1024 B reserved
    int*    eoff    = (int*)(ws + 3 * nb + 1024);
    int2*   csr     = (int2*)(ws + 3 * nb + 1024 + (size_t)e * 4);
    __bf16* pw      = (__bf16*)(ws + 3 * nb + 1024 + (size_t)e * 12);  // 64 KB packed (W1|W2)
    __bf16* z1      = (__bf16*)(ws + 3 * nb + 1024 + (size_t)e * 12 + 65536);
    __bf16* h1      = z1 + (size_t)n * D;
    __bf16* z2      = h1 + (size_t)n * D;

    hipMemsetAsync(counts, 0, nb, stream);

    int e4b = (e / 4 + 255) / 256 + 1;
    int sb = (n + 2047) / 2048;
    int gb = (n + 63) / 64;
    int ab = ((n * 16) + 255) / 256;

    count_kernel<<<e4b, 256, 0, stream>>>(dst, counts, eoff, e);
    dinv_kernel<<<(n + 255) / 256, 256, 0, stream>>>(counts, dinv, n);
    scan_part<<<sb, 256, 0, stream>>>(counts, partial, n);
    scan_top<<<1, 256, 0, stream>>>(partial, sb);
    scan_down<<<sb, 256, 0, stream>>>(counts, partial, rowptr, n);
    fill_kernel<<<e4b, 256, 0, stream>>>(src, dst, rowptr, eoff, dinv, csr, e);
    pack_w<<<128, 256, 0, stream>>>(W1, W2, pw);

    // layer 1
    gemm1_mfma<<<gb, 256, 0, stream>>>(x, pw, z1, n);
    agg1_kernel<<<ab, 256, 0, stream>>>(z1, rowptr, counts, csr, dinv, b1, h1, n);
    // layer 2
    gemm2_mfma<<<gb, 256, 0, stream>>>(h1, pw + 16384, z2, n);
    agg2_fc_kernel<<<ab, 256, 0, stream>>>(z2, rowptr, counts, csr, dinv, b2, Wfc, bfc, out, n);
}